// Round 4
// baseline (876.934 us; speedup 1.0000x reference)
//
#include <hip/hip_runtime.h>
#include <math.h>

#define NN 50000
#define NE 800000
#define NG 64

// ---- CSR build: count ----
__global__ void k_count(const int* __restrict__ esrc, const int* __restrict__ edst,
                        int* __restrict__ indeg, int* __restrict__ outdeg, int E)
{
  int e = blockIdx.x*blockDim.x + threadIdx.x;
  if (e >= E) return;
  atomicAdd(indeg + edst[e], 1);
  atomicAdd(outdeg + esrc[e], 1);
}

// ---- CSR build: single-block exclusive prefix scan over N=50000 ----
__global__ void __launch_bounds__(1024) k_prefix(const int* __restrict__ indeg,
                                                 int* __restrict__ rowptr, int N)
{
  __shared__ int tot[1024];
  int t = threadIdx.x;
  int chunk = (N + 1023) / 1024;
  int lo = t*chunk, hi = lo + chunk; if (hi > N) hi = N; if (lo > N) lo = N;
  int s = 0;
  for (int i = lo; i < hi; ++i) s += indeg[i];
  tot[t] = s;
  __syncthreads();
  for (int off = 1; off < 1024; off <<= 1) {
    int v = 0;
    if (t >= off) v = tot[t-off];
    __syncthreads();
    if (t >= off) tot[t] += v;
    __syncthreads();
  }
  int base = (t == 0) ? 0 : tot[t-1];
  for (int i = lo; i < hi; ++i) {
    rowptr[i] = base;
    base += indeg[i];
  }
  if (t == 1023) rowptr[N] = tot[1023];
}

// ---- CSR build: fill; single int2{src,eid} 8B write per edge ----
__global__ void k_fill(const int* __restrict__ esrc, const int* __restrict__ edst,
                       const int* __restrict__ rowptr, int* __restrict__ cursor,
                       int2* __restrict__ csr, int E)
{
  int e = blockIdx.x*blockDim.x + threadIdx.x;
  if (e >= E) return;
  int d = edst[e];
  int slot = rowptr[d] + atomicAdd(cursor + d, 1);
  csr[slot] = make_int2(esrc[e], e);
}

// ---- init: gather sh over CSR run + concat scalars -> svd0 [N,18] ----
__global__ void k_init_svd0(const float* __restrict__ xs,
                            const float* __restrict__ evec,
                            const int2* __restrict__ csr,
                            const int* __restrict__ rowptr,
                            float* __restrict__ svd0, int N)
{
  int n = blockIdx.x*blockDim.x + threadIdx.x;
  if (n >= N) return;
  int b = rowptr[n], e2 = rowptr[n+1];
  float acc[9];
  #pragma unroll
  for (int j = 0; j < 9; ++j) acc[j] = 0.f;
  const float s3  = 1.7320508075688772f;
  const float s15 = 3.872983346207417f;
  const float s5  = 2.23606797749979f;
  for (int s = b; s < e2; ++s) {
    int eid = csr[s].y;
    float vx = evec[3*eid+0], vy = evec[3*eid+1], vz = evec[3*eid+2];
    float r = sqrtf(vx*vx + vy*vy + vz*vz + 1e-12f);
    float x = vx / r, y = vy / r, z = vz / r;
    acc[0] += 1.f;
    acc[1] += s3*x; acc[2] += s3*y; acc[3] += s3*z;
    acc[4] += s15*x*z;
    acc[5] += s15*x*y;
    acc[6] += s5*(y*y - 0.5f*(x*x + z*z));
    acc[7] += s15*y*z;
    acc[8] += 0.5f*s15*(z*z - x*x);
  }
  int dg = e2 - b;
  float inv = 1.f / (float)(dg > 1 ? dg : 1);
  float* o = svd0 + (size_t)n*18;
  const float* xrow = xs + (size_t)n*9;
  #pragma unroll
  for (int j = 0; j < 9; ++j) o[j] = xrow[j];
  #pragma unroll
  for (int j = 0; j < 9; ++j) o[9+j] = acc[j]*inv;
}

// ---- kernel A: node-level q/k/v features; q is pre-contracted with Wd ----
template<int CS, int CV>
__global__ void __launch_bounds__(256) k_node_feats(
    const float* __restrict__ in,
    const float* __restrict__ W0,  // [3,CS,8]
    const float* __restrict__ W1,  // [3,CV,8]
    const float* __restrict__ W2,  // [3,CV,8]
    const float* __restrict__ Wd,  // [3,8,8]
    float* __restrict__ qt,
    float* __restrict__ kf,
    float* __restrict__ vf,
    int N)
{
  int n = blockIdx.x*blockDim.x + threadIdx.x;
  if (n >= N) return;
  const float* x = in + (size_t)n*(CS + 8*CV);
  float s_in[CS];
  float v_in[CV][3];
  float d_in[CV][5];
  #pragma unroll
  for (int i = 0; i < CS; ++i) s_in[i] = x[i];
  #pragma unroll
  for (int i = 0; i < CV; ++i)
    #pragma unroll
    for (int m = 0; m < 3; ++m) v_in[i][m] = x[CS + i*3 + m];
  #pragma unroll
  for (int i = 0; i < CV; ++i)
    #pragma unroll
    for (int m = 0; m < 5; ++m) d_in[i][m] = x[CS + 3*CV + i*5 + m];

  const float inv_s3 = 0.5773502691896258f;
  const float inv_s5 = 0.4472135954999579f;

  #pragma unroll
  for (int t = 0; t < 3; ++t) {
    float ss[8];
    float vv[8][3];
    float dd[8][5];
    #pragma unroll
    for (int c = 0; c < 8; ++c) {
      float a = 0.f;
      #pragma unroll
      for (int i = 0; i < CS; ++i) a += s_in[i]*W0[t*CS*8 + i*8 + c];
      ss[c] = a;
    }
    #pragma unroll
    for (int c = 0; c < 8; ++c)
      #pragma unroll
      for (int m = 0; m < 3; ++m) {
        float a = 0.f;
        #pragma unroll
        for (int i = 0; i < CV; ++i) a += v_in[i][m]*W1[t*CV*8 + i*8 + c];
        vv[c][m] = a;
      }
    #pragma unroll
    for (int c = 0; c < 8; ++c)
      #pragma unroll
      for (int m = 0; m < 5; ++m) {
        float a = 0.f;
        #pragma unroll
        for (int i = 0; i < CV; ++i) a += d_in[i][m]*W2[t*CV*8 + i*8 + c];
        dd[c][m] = a;
      }

    if (t == 0) {
      float* q = qt + (size_t)n*72;
      #pragma unroll
      for (int dp = 0; dp < 8; ++dp) {
        float a = 0.f;
        #pragma unroll
        for (int c = 0; c < 8; ++c) a += ss[c]*Wd[0*64 + c*8 + dp];
        q[dp] = a;
      }
      #pragma unroll
      for (int dp = 0; dp < 8; ++dp)
        #pragma unroll
        for (int m = 0; m < 3; ++m) {
          float a = 0.f;
          #pragma unroll
          for (int c = 0; c < 8; ++c) a += vv[c][m]*Wd[1*64 + c*8 + dp];
          q[8 + dp*3 + m] = a*inv_s3;
        }
      #pragma unroll
      for (int dp = 0; dp < 8; ++dp)
        #pragma unroll
        for (int m = 0; m < 5; ++m) {
          float a = 0.f;
          #pragma unroll
          for (int c = 0; c < 8; ++c) a += dd[c][m]*Wd[2*64 + c*8 + dp];
          q[32 + dp*5 + m] = a*inv_s5;
        }
    } else {
      float* o = (t == 1 ? kf : vf) + (size_t)n*72;
      #pragma unroll
      for (int c = 0; c < 8; ++c) o[c] = ss[c];
      #pragma unroll
      for (int c = 0; c < 8; ++c)
        #pragma unroll
        for (int m = 0; m < 3; ++m) o[8 + c*3 + m] = vv[c][m];
      #pragma unroll
      for (int c = 0; c < 8; ++c)
        #pragma unroll
        for (int m = 0; m < 5; ++m) o[32 + c*5 + m] = dd[c][m];
    }
  }
}

// ---- fused attention: per-node logits (LDS) + softmax + weighted gather ----
#define AT_NODES 32
#define AT_CAP 64

__device__ __forceinline__ float dot72(const float* __restrict__ q,
                                       const float* __restrict__ krow)
{
  const float4* kb = (const float4*)krow;
  float d0 = 0.f;
  #pragma unroll 9
  for (int u = 0; u < 18; ++u) {
    float4 kk = kb[u];
    d0 += q[u*4+0]*kk.x + q[u*4+1]*kk.y + q[u*4+2]*kk.z + q[u*4+3]*kk.w;
  }
  return d0;
}

__global__ void __launch_bounds__(576) k_attn(
    const float* __restrict__ qt,
    const float* __restrict__ kf,
    const float* __restrict__ vf,
    const int2* __restrict__ csr,
    const int* __restrict__ rowptr,
    const float* __restrict__ base,   // residual input or nullptr
    float* __restrict__ out, int N)
{
  __shared__ float qls[AT_NODES][72];   // 9216 B
  __shared__ float lg[AT_NODES][AT_CAP];// 8192 B
  int t = threadIdx.x;
  int grp = t/18, j = t - grp*18;
  int n = blockIdx.x*AT_NODES + grp;

  // cooperative load of 32 qt rows (2304 floats = 576 threads x float4)
  {
    size_t g = (size_t)blockIdx.x*AT_NODES*72 + (size_t)t*4;
    float4 v = make_float4(0.f,0.f,0.f,0.f);
    if (g < (size_t)N*72) v = *(const float4*)(qt + g);
    float* qf = (float*)qls;
    *(float4*)&qf[t*4] = v;
  }
  __syncthreads();

  int b = 0, e2 = 0;
  if (n < N) { b = rowptr[n]; e2 = rowptr[n+1]; }
  const float* q = qls[grp];

  // pass 1: logits for this node's run (lane j takes slots b+j, b+j+18, ...)
  for (int s = b + j; s < e2; s += 18) {
    int r = s - b;
    float d0 = dot72(q, kf + (size_t)csr[s].x*72);
    if (r < AT_CAP) lg[grp][r] = d0;
  }
  __syncthreads();

  if (n >= N) return;
  int deg = e2 - b;
  float mx = -3.4e38f;
  for (int r = 0; r < deg; ++r) {
    float lv = (r < AT_CAP) ? lg[grp][r] : dot72(q, kf + (size_t)csr[b+r].x*72);
    mx = fmaxf(mx, lv);
  }
  float sum = 0.f;
  for (int r = 0; r < deg; ++r) {
    float lv = (r < AT_CAP) ? lg[grp][r] : dot72(q, kf + (size_t)csr[b+r].x*72);
    sum += expf(lv - mx);
  }
  float inv = 1.f / sum;
  float ax = 0.f, ay = 0.f, az = 0.f, aw = 0.f;
  for (int r = 0; r < deg; ++r) {
    float lv = (r < AT_CAP) ? lg[grp][r] : dot72(q, kf + (size_t)csr[b+r].x*72);
    float wv = sqrtf(expf(lv - mx) * inv);
    const float4 v = *(const float4*)(vf + (size_t)csr[b+r].x*72 + j*4);
    ax += wv*v.x; ay += wv*v.y; az += wv*v.z; aw += wv*v.w;
  }
  if (base) {
    const float4 bb = *(const float4*)(base + (size_t)n*72 + j*4);
    ax += bb.x; ay += bb.y; az += bb.z; aw += bb.w;
  }
  float4 r4; r4.x = ax; r4.y = ay; r4.z = az; r4.w = aw;
  *(float4*)(out + (size_t)n*72 + j*4) = r4;
}

// ---- fused head: 64 nodes/block, 256 threads, register-tiled GEMM ----
#define HD_NODES 64
__global__ void __launch_bounds__(256) k_head(
    const float* __restrict__ svd,   // [N,72], s = first 8
    const float* __restrict__ Wol,   // [8,128]
    const float* __restrict__ Wlin,  // [2,128,128]
    const float* __restrict__ blin,  // [2,128]
    const int* __restrict__ outdeg,
    const int* __restrict__ bseg,
    float* __restrict__ m,           // [G,128] atomic
    float* __restrict__ cg,          // [G] atomic
    int N)
{
  __shared__ float hs[HD_NODES][128];   // 32 KB
  __shared__ float ssm[HD_NODES][8];    // 2 KB
  __shared__ float nrm_p[HD_NODES][33]; // 8.4 KB (padded vs bank conflicts)
  __shared__ float rinv[HD_NODES];
  int t = threadIdx.x;
  int n0 = blockIdx.x*HD_NODES;
  int tc = t & 31, tr = t >> 5;   // 32 col-groups x 8 node-groups
  int c0 = tc*4;
  int nb = tr*8;

  // load s (first 8 floats of each svd row): 4 threads/node, float2 each
  {
    int node = t >> 2, p = t & 3;
    int gn = n0 + node;
    float2 v = make_float2(0.f, 0.f);
    if (gn < N) v = *(const float2*)(svd + (size_t)gn*72 + p*2);
    ssm[node][p*2] = v.x; ssm[node][p*2+1] = v.y;
  }
  __syncthreads();

  // L1: h = s @ Wol (8 -> 128), pre-norm
  float acc[8][4];
  #pragma unroll
  for (int nd = 0; nd < 8; ++nd)
    #pragma unroll
    for (int cc = 0; cc < 4; ++cc) acc[nd][cc] = 0.f;
  #pragma unroll
  for (int i = 0; i < 8; ++i) {
    float4 wv = *(const float4*)(Wol + i*128 + c0);
    #pragma unroll
    for (int nd = 0; nd < 8; ++nd) {
      float a = ssm[nb+nd][i];
      acc[nd][0] += a*wv.x; acc[nd][1] += a*wv.y;
      acc[nd][2] += a*wv.z; acc[nd][3] += a*wv.w;
    }
  }
  // write pre-norm h; square partials from REGISTERS
  #pragma unroll
  for (int nd = 0; nd < 8; ++nd) {
    *(float4*)&hs[nb+nd][c0] = make_float4(acc[nd][0],acc[nd][1],acc[nd][2],acc[nd][3]);
    nrm_p[nb+nd][tc] = acc[nd][0]*acc[nd][0] + acc[nd][1]*acc[nd][1]
                     + acc[nd][2]*acc[nd][2] + acc[nd][3]*acc[nd][3];
  }
  __syncthreads();
  if (t < HD_NODES) {
    float sq = 0.f;
    #pragma unroll
    for (int k = 0; k < 32; ++k) sq += nrm_p[t][k];
    rinv[t] = 1.f / fmaxf(sqrtf(sq), 1e-12f);
  }
  __syncthreads();
  // apply norm + relu (linear sweep, conflict-free)
  #pragma unroll
  for (int k = 0; k < 32; ++k) {
    int idx = t + k*256;
    int node = idx >> 7, c = idx & 127;
    hs[node][c] = fmaxf(hs[node][c]*rinv[node], 0.f);
  }
  __syncthreads();

  // two 128x128 layers
  for (int l = 0; l < 2; ++l) {
    float4 bv = *(const float4*)(blin + l*128 + c0);
    float a2[8][4];
    #pragma unroll
    for (int nd = 0; nd < 8; ++nd) {
      a2[nd][0]=bv.x; a2[nd][1]=bv.y; a2[nd][2]=bv.z; a2[nd][3]=bv.w;
    }
    for (int i = 0; i < 128; i += 4) {
      float av[8][4];
      #pragma unroll
      for (int nd = 0; nd < 8; ++nd)
        *(float4*)av[nd] = *(const float4*)&hs[nb+nd][i];
      #pragma unroll
      for (int ii = 0; ii < 4; ++ii) {
        float4 wv = *(const float4*)(Wlin + l*16384 + (i+ii)*128 + c0);
        #pragma unroll
        for (int nd = 0; nd < 8; ++nd) {
          a2[nd][0] += av[nd][ii]*wv.x;
          a2[nd][1] += av[nd][ii]*wv.y;
          a2[nd][2] += av[nd][ii]*wv.z;
          a2[nd][3] += av[nd][ii]*wv.w;
        }
      }
    }
    __syncthreads();
    #pragma unroll
    for (int nd = 0; nd < 8; ++nd)
      *(float4*)&hs[nb+nd][c0] = make_float4(
          fmaxf(a2[nd][0],0.f), fmaxf(a2[nd][1],0.f),
          fmaxf(a2[nd][2],0.f), fmaxf(a2[nd][3],0.f));
    __syncthreads();
  }

  // group pooling (bseg sorted -> run-length accumulate)
  if (t < 128) {
    int c = t;
    float accm = 0.f; int gprev = -1;
    for (int nn = 0; nn < HD_NODES; ++nn) {
      int n = n0 + nn;
      if (n >= N) break;
      int g = bseg[n];
      if (g != gprev) {
        if (gprev >= 0) atomicAdd(&m[gprev*128 + c], accm);
        accm = 0.f; gprev = g;
      }
      accm += (float)outdeg[n]*hs[nn][c];
    }
    if (gprev >= 0) atomicAdd(&m[gprev*128 + c], accm);
  } else if (t == 128) {
    float a = 0.f; int gp = -1;
    for (int nn = 0; nn < HD_NODES; ++nn) {
      int n = n0 + nn;
      if (n >= N) break;
      int g = bseg[n];
      if (g != gp) {
        if (gp >= 0) atomicAdd(&cg[gp], a);
        a = 0.f; gp = g;
      }
      a += (float)outdeg[n];
    }
    if (gp >= 0) atomicAdd(&cg[gp], a);
  }
}

// ---- final: softmax((m/cg) @ Wout + bout) ----
__global__ void k_out(const float* __restrict__ m, const float* __restrict__ cg,
                      const float* __restrict__ Wout, const float* __restrict__ bout,
                      float* __restrict__ out)
{
  int g = threadIdx.x;
  if (g >= NG) return;
  float inv = 1.f / fmaxf(cg[g], 1.f);
  float v[9];
  #pragma unroll
  for (int j = 0; j < 9; ++j) {
    float a = 0.f;
    for (int i = 0; i < 128; ++i) a += m[g*128 + i]*Wout[i*9 + j];
    v[j] = a*inv + bout[j];
  }
  float mxv = v[0];
  #pragma unroll
  for (int j = 1; j < 9; ++j) mxv = fmaxf(mxv, v[j]);
  float sum = 0.f;
  #pragma unroll
  for (int j = 0; j < 9; ++j) { v[j] = expf(v[j] - mxv); sum += v[j]; }
  #pragma unroll
  for (int j = 0; j < 9; ++j) out[g*9 + j] = v[j]/sum;
}

extern "C" void kernel_launch(void* const* d_in, const int* in_sizes, int n_in,
                              void* d_out, int out_size, void* d_ws, size_t ws_size,
                              hipStream_t stream) {
  (void)in_sizes; (void)n_in; (void)out_size; (void)ws_size;
  const float* x_scalars = (const float*)d_in[0];
  const float* edge_vec  = (const float*)d_in[1];
  const float* et0_W0    = (const float*)d_in[2];
  const float* et0_W1    = (const float*)d_in[3];
  const float* et0_W2    = (const float*)d_in[4];
  const float* et0_Wd    = (const float*)d_in[5];
  const float* h_W0      = (const float*)d_in[6];
  const float* h_W1      = (const float*)d_in[7];
  const float* h_W2      = (const float*)d_in[8];
  const float* h_Wd      = (const float*)d_in[9];
  const float* Wol       = (const float*)d_in[10];
  const float* Wlin      = (const float*)d_in[11];
  const float* blin      = (const float*)d_in[12];
  const float* Wout      = (const float*)d_in[13];
  const float* bout      = (const float*)d_in[14];
  const int*   esrc      = (const int*)d_in[15];
  const int*   edst      = (const int*)d_in[16];
  const int*   bseg      = (const int*)d_in[17];

  const int N = NN, E = NE;

  char* w = (char*)d_ws;
  auto alloc = [&](size_t nbytes) {
    char* p = w;
    w += (nbytes + 255) & ~(size_t)255;
    return p;
  };
  int*   indeg   = (int*)  alloc((size_t)N*4);
  int*   outdeg  = (int*)  alloc((size_t)N*4);
  int*   cursor  = (int*)  alloc((size_t)N*4);
  int*   rowptr  = (int*)  alloc((size_t)(N+1)*4);
  int2*  csr     = (int2*) alloc((size_t)E*8);
  float* svd0    = (float*)alloc((size_t)N*18*4);
  float* stA     = (float*)alloc((size_t)N*72*4);
  float* stB     = (float*)alloc((size_t)N*72*4);
  float* qt      = (float*)alloc((size_t)N*72*4);
  float* kf      = (float*)alloc((size_t)N*72*4);
  float* vf      = (float*)alloc((size_t)N*72*4);
  float* mpool   = (float*)alloc((size_t)NG*128*4);
  float* cgp     = (float*)alloc((size_t)NG*4);

  hipMemsetAsync(indeg,   0, (size_t)N*4, stream);
  hipMemsetAsync(outdeg,  0, (size_t)N*4, stream);
  hipMemsetAsync(cursor,  0, (size_t)N*4, stream);
  hipMemsetAsync(mpool,   0, (size_t)NG*128*4, stream);
  hipMemsetAsync(cgp,     0, (size_t)NG*4, stream);

  const int TB = 256;
  const int gE = (E + TB - 1) / TB;
  const int gN = (N + TB - 1) / TB;
  const int gAT = (N + AT_NODES - 1) / AT_NODES;
  const int gHD = (N + HD_NODES - 1) / HD_NODES;

  // CSR build, then sh gather + init
  k_count<<<gE, TB, 0, stream>>>(esrc, edst, indeg, outdeg, E);
  k_prefix<<<1, 1024, 0, stream>>>(indeg, rowptr, N);
  k_fill<<<gE, TB, 0, stream>>>(esrc, edst, rowptr, cursor, csr, E);
  k_init_svd0<<<gN, TB, 0, stream>>>(x_scalars, edge_vec, csr, rowptr, svd0, N);

  // ---- et0 layer (no residual) ----
  k_node_feats<10,1><<<gN, TB, 0, stream>>>(svd0, et0_W0, et0_W1, et0_W2, et0_Wd, qt, kf, vf, N);
  k_attn<<<gAT, 576, 0, stream>>>(qt, kf, vf, csr, rowptr, nullptr, stA, N);

  // ---- 2 hidden layers with residual ----
  float* cur = stA; float* oth = stB;
  for (int l = 0; l < 2; ++l) {
    k_node_feats<8,8><<<gN, TB, 0, stream>>>(cur, h_W0 + l*192, h_W1 + l*192,
                                             h_W2 + l*192, h_Wd + l*192, qt, kf, vf, N);
    k_attn<<<gAT, 576, 0, stream>>>(qt, kf, vf, csr, rowptr, cur, oth, N);
    float* t = cur; cur = oth; oth = t;
  }

  // ---- fused MLP head + group pooling ----
  k_head<<<gHD, 256, 0, stream>>>(cur, Wol, Wlin, blin, outdeg, bseg, mpool, cgp, N);
  k_out<<<1, 64, 0, stream>>>(mpool, cgp, Wout, bout, (float*)d_out);
}

// Round 5
// 802.419 us; speedup vs baseline: 1.0929x; 1.0929x over previous
//
#include <hip/hip_runtime.h>
#include <math.h>

#define NN 50000
#define NE 800000
#define NG 64
#define FSTRIDE 80   // qt/kf/vf row stride: 320 B = 5 full 64B lines, 64B-aligned

// ---- CSR build: count ----
__global__ void k_count(const int* __restrict__ esrc, const int* __restrict__ edst,
                        int* __restrict__ indeg, int* __restrict__ outdeg, int E)
{
  int e = blockIdx.x*blockDim.x + threadIdx.x;
  if (e >= E) return;
  atomicAdd(indeg + edst[e], 1);
  atomicAdd(outdeg + esrc[e], 1);
}

// ---- CSR build: single-block exclusive prefix scan over N=50000 ----
__global__ void __launch_bounds__(1024) k_prefix(const int* __restrict__ indeg,
                                                 int* __restrict__ rowptr, int N)
{
  __shared__ int tot[1024];
  int t = threadIdx.x;
  int chunk = (N + 1023) / 1024;
  int lo = t*chunk, hi = lo + chunk; if (hi > N) hi = N; if (lo > N) lo = N;
  int s = 0;
  for (int i = lo; i < hi; ++i) s += indeg[i];
  tot[t] = s;
  __syncthreads();
  for (int off = 1; off < 1024; off <<= 1) {
    int v = 0;
    if (t >= off) v = tot[t-off];
    __syncthreads();
    if (t >= off) tot[t] += v;
    __syncthreads();
  }
  int base = (t == 0) ? 0 : tot[t-1];
  for (int i = lo; i < hi; ++i) {
    rowptr[i] = base;
    base += indeg[i];
  }
  if (t == 1023) rowptr[N] = tot[1023];
}

// ---- CSR build: fill; single int2{src,eid} 8B write per edge ----
__global__ void k_fill(const int* __restrict__ esrc, const int* __restrict__ edst,
                       const int* __restrict__ rowptr, int* __restrict__ cursor,
                       int2* __restrict__ csr, int E)
{
  int e = blockIdx.x*blockDim.x + threadIdx.x;
  if (e >= E) return;
  int d = edst[e];
  int slot = rowptr[d] + atomicAdd(cursor + d, 1);
  csr[slot] = make_int2(esrc[e], e);
}

// ---- init: gather sh over CSR run + concat scalars -> svd0 [N,18] ----
__global__ void k_init_svd0(const float* __restrict__ xs,
                            const float* __restrict__ evec,
                            const int2* __restrict__ csr,
                            const int* __restrict__ rowptr,
                            float* __restrict__ svd0, int N)
{
  int n = blockIdx.x*blockDim.x + threadIdx.x;
  if (n >= N) return;
  int b = rowptr[n], e2 = rowptr[n+1];
  float acc[9];
  #pragma unroll
  for (int j = 0; j < 9; ++j) acc[j] = 0.f;
  const float s3  = 1.7320508075688772f;
  const float s15 = 3.872983346207417f;
  const float s5  = 2.23606797749979f;
  for (int s = b; s < e2; ++s) {
    int eid = csr[s].y;
    float vx = evec[3*eid+0], vy = evec[3*eid+1], vz = evec[3*eid+2];
    float r = sqrtf(vx*vx + vy*vy + vz*vz + 1e-12f);
    float x = vx / r, y = vy / r, z = vz / r;
    acc[0] += 1.f;
    acc[1] += s3*x; acc[2] += s3*y; acc[3] += s3*z;
    acc[4] += s15*x*z;
    acc[5] += s15*x*y;
    acc[6] += s5*(y*y - 0.5f*(x*x + z*z));
    acc[7] += s15*y*z;
    acc[8] += 0.5f*s15*(z*z - x*x);
  }
  int dg = e2 - b;
  float inv = 1.f / (float)(dg > 1 ? dg : 1);
  float* o = svd0 + (size_t)n*18;
  const float* xrow = xs + (size_t)n*9;
  #pragma unroll
  for (int j = 0; j < 9; ++j) o[j] = xrow[j];
  #pragma unroll
  for (int j = 0; j < 9; ++j) o[9+j] = acc[j]*inv;
}

// ---- kernel A: node-level q/k/v features; q is pre-contracted with Wd ----
// outputs use FSTRIDE(80)-float rows, 64B-aligned
template<int CS, int CV>
__global__ void __launch_bounds__(256) k_node_feats(
    const float* __restrict__ in,
    const float* __restrict__ W0,  // [3,CS,8]
    const float* __restrict__ W1,  // [3,CV,8]
    const float* __restrict__ W2,  // [3,CV,8]
    const float* __restrict__ Wd,  // [3,8,8]
    float* __restrict__ qt,
    float* __restrict__ kf,
    float* __restrict__ vf,
    int N)
{
  int n = blockIdx.x*blockDim.x + threadIdx.x;
  if (n >= N) return;
  const float* x = in + (size_t)n*(CS + 8*CV);
  float s_in[CS];
  float v_in[CV][3];
  float d_in[CV][5];
  #pragma unroll
  for (int i = 0; i < CS; ++i) s_in[i] = x[i];
  #pragma unroll
  for (int i = 0; i < CV; ++i)
    #pragma unroll
    for (int m = 0; m < 3; ++m) v_in[i][m] = x[CS + i*3 + m];
  #pragma unroll
  for (int i = 0; i < CV; ++i)
    #pragma unroll
    for (int m = 0; m < 5; ++m) d_in[i][m] = x[CS + 3*CV + i*5 + m];

  const float inv_s3 = 0.5773502691896258f;
  const float inv_s5 = 0.4472135954999579f;

  #pragma unroll
  for (int t = 0; t < 3; ++t) {
    float ss[8];
    float vv[8][3];
    float dd[8][5];
    #pragma unroll
    for (int c = 0; c < 8; ++c) {
      float a = 0.f;
      #pragma unroll
      for (int i = 0; i < CS; ++i) a += s_in[i]*W0[t*CS*8 + i*8 + c];
      ss[c] = a;
    }
    #pragma unroll
    for (int c = 0; c < 8; ++c)
      #pragma unroll
      for (int m = 0; m < 3; ++m) {
        float a = 0.f;
        #pragma unroll
        for (int i = 0; i < CV; ++i) a += v_in[i][m]*W1[t*CV*8 + i*8 + c];
        vv[c][m] = a;
      }
    #pragma unroll
    for (int c = 0; c < 8; ++c)
      #pragma unroll
      for (int m = 0; m < 5; ++m) {
        float a = 0.f;
        #pragma unroll
        for (int i = 0; i < CV; ++i) a += d_in[i][m]*W2[t*CV*8 + i*8 + c];
        dd[c][m] = a;
      }

    if (t == 0) {
      float* q = qt + (size_t)n*FSTRIDE;
      #pragma unroll
      for (int dp = 0; dp < 8; ++dp) {
        float a = 0.f;
        #pragma unroll
        for (int c = 0; c < 8; ++c) a += ss[c]*Wd[0*64 + c*8 + dp];
        q[dp] = a;
      }
      #pragma unroll
      for (int dp = 0; dp < 8; ++dp)
        #pragma unroll
        for (int m = 0; m < 3; ++m) {
          float a = 0.f;
          #pragma unroll
          for (int c = 0; c < 8; ++c) a += vv[c][m]*Wd[1*64 + c*8 + dp];
          q[8 + dp*3 + m] = a*inv_s3;
        }
      #pragma unroll
      for (int dp = 0; dp < 8; ++dp)
        #pragma unroll
        for (int m = 0; m < 5; ++m) {
          float a = 0.f;
          #pragma unroll
          for (int c = 0; c < 8; ++c) a += dd[c][m]*Wd[2*64 + c*8 + dp];
          q[32 + dp*5 + m] = a*inv_s5;
        }
    } else {
      float* o = (t == 1 ? kf : vf) + (size_t)n*FSTRIDE;
      #pragma unroll
      for (int c = 0; c < 8; ++c) o[c] = ss[c];
      #pragma unroll
      for (int c = 0; c < 8; ++c)
        #pragma unroll
        for (int m = 0; m < 3; ++m) o[8 + c*3 + m] = vv[c][m];
      #pragma unroll
      for (int c = 0; c < 8; ++c)
        #pragma unroll
        for (int m = 0; m < 5; ++m) o[32 + c*5 + m] = dd[c][m];
    }
  }
}

// ---- kernel B: slot-parallel logit; dst-sorted so qt rows hit L1 ----
__global__ void k_edge_logit2(const float* __restrict__ qt,
                              const float* __restrict__ kf,
                              const int2* __restrict__ csr,
                              const int* __restrict__ csr_dst,
                              float* __restrict__ elog, int E)
{
  int s = blockIdx.x*blockDim.x + threadIdx.x;
  if (s >= E) return;
  const float4* qa = (const float4*)(qt + (size_t)csr_dst[s]*FSTRIDE);
  const float4* kb = (const float4*)(kf + (size_t)csr[s].x*FSTRIDE);
  float acc = 0.f;
  #pragma unroll
  for (int j = 0; j < 18; ++j) {
    float4 a = qa[j], b = kb[j];
    acc += a.x*b.x + a.y*b.y + a.z*b.z + a.w*b.w;
  }
  elog[s] = acc;
}

// ---- kernel D: per-node online softmax + weighted gather, 18 threads/node ----
#define GA_NODES 32
__global__ void __launch_bounds__(576) k_attn_gather(
    const float* __restrict__ elog,
    const float* __restrict__ vf,
    const int2* __restrict__ csr,
    const int* __restrict__ rowptr,
    const float* __restrict__ base,   // residual input or nullptr
    float* __restrict__ out, int N)
{
  int t = threadIdx.x;
  int n = blockIdx.x*GA_NODES + t/18;
  int j = t - (t/18)*18;
  if (n >= N) return;
  int b = rowptr[n], e2 = rowptr[n+1];
  float ax = 0.f, ay = 0.f, az = 0.f, aw = 0.f;
  if (e2 > b) {
    // online softmax statistics (single pass)
    float mx = -3.4e38f, sum = 0.f;
    for (int s = b; s < e2; ++s) {
      float l = elog[s];
      float m2 = fmaxf(mx, l);
      sum = sum*expf(mx - m2) + expf(l - m2);
      mx = m2;
    }
    float inv = 1.f / sum;
    for (int s = b; s < e2; ++s) {
      float wv = sqrtf(expf(elog[s] - mx) * inv);
      const float4 v = *(const float4*)(vf + (size_t)csr[s].x*FSTRIDE + j*4);
      ax += wv*v.x; ay += wv*v.y; az += wv*v.z; aw += wv*v.w;
    }
  }
  if (base) {
    const float4 bb = *(const float4*)(base + (size_t)n*72 + j*4);
    ax += bb.x; ay += bb.y; az += bb.z; aw += bb.w;
  }
  float4 r; r.x = ax; r.y = ay; r.z = az; r.w = aw;
  *(float4*)(out + (size_t)n*72 + j*4) = r;
}

// ---- fused head: 64 nodes/block, 256 threads, register-tiled GEMM ----
#define HD_NODES 64
__global__ void __launch_bounds__(256) k_head(
    const float* __restrict__ svd,   // [N,72], s = first 8
    const float* __restrict__ Wol,   // [8,128]
    const float* __restrict__ Wlin,  // [2,128,128]
    const float* __restrict__ blin,  // [2,128]
    const int* __restrict__ outdeg,
    const int* __restrict__ bseg,
    float* __restrict__ m,           // [G,128] atomic
    float* __restrict__ cg,          // [G] atomic
    int N)
{
  __shared__ float hs[HD_NODES][128];   // 32 KB
  __shared__ float ssm[HD_NODES][8];    // 2 KB
  __shared__ float nrm_p[HD_NODES][33]; // 8.4 KB (padded vs bank conflicts)
  __shared__ float rinv[HD_NODES];
  int t = threadIdx.x;
  int n0 = blockIdx.x*HD_NODES;
  int tc = t & 31, tr = t >> 5;   // 32 col-groups x 8 node-groups
  int c0 = tc*4;
  int nb = tr*8;

  {
    int node = t >> 2, p = t & 3;
    int gn = n0 + node;
    float2 v = make_float2(0.f, 0.f);
    if (gn < N) v = *(const float2*)(svd + (size_t)gn*72 + p*2);
    ssm[node][p*2] = v.x; ssm[node][p*2+1] = v.y;
  }
  __syncthreads();

  // L1: h = s @ Wol (8 -> 128), pre-norm
  float acc[8][4];
  #pragma unroll
  for (int nd = 0; nd < 8; ++nd)
    #pragma unroll
    for (int cc = 0; cc < 4; ++cc) acc[nd][cc] = 0.f;
  #pragma unroll
  for (int i = 0; i < 8; ++i) {
    float4 wv = *(const float4*)(Wol + i*128 + c0);
    #pragma unroll
    for (int nd = 0; nd < 8; ++nd) {
      float a = ssm[nb+nd][i];
      acc[nd][0] += a*wv.x; acc[nd][1] += a*wv.y;
      acc[nd][2] += a*wv.z; acc[nd][3] += a*wv.w;
    }
  }
  #pragma unroll
  for (int nd = 0; nd < 8; ++nd) {
    *(float4*)&hs[nb+nd][c0] = make_float4(acc[nd][0],acc[nd][1],acc[nd][2],acc[nd][3]);
    nrm_p[nb+nd][tc] = acc[nd][0]*acc[nd][0] + acc[nd][1]*acc[nd][1]
                     + acc[nd][2]*acc[nd][2] + acc[nd][3]*acc[nd][3];
  }
  __syncthreads();
  if (t < HD_NODES) {
    float sq = 0.f;
    #pragma unroll
    for (int k = 0; k < 32; ++k) sq += nrm_p[t][k];
    rinv[t] = 1.f / fmaxf(sqrtf(sq), 1e-12f);
  }
  __syncthreads();
  #pragma unroll
  for (int k = 0; k < 32; ++k) {
    int idx = t + k*256;
    int node = idx >> 7, c = idx & 127;
    hs[node][c] = fmaxf(hs[node][c]*rinv[node], 0.f);
  }
  __syncthreads();

  for (int l = 0; l < 2; ++l) {
    float4 bv = *(const float4*)(blin + l*128 + c0);
    float a2[8][4];
    #pragma unroll
    for (int nd = 0; nd < 8; ++nd) {
      a2[nd][0]=bv.x; a2[nd][1]=bv.y; a2[nd][2]=bv.z; a2[nd][3]=bv.w;
    }
    for (int i = 0; i < 128; i += 4) {
      float av[8][4];
      #pragma unroll
      for (int nd = 0; nd < 8; ++nd)
        *(float4*)av[nd] = *(const float4*)&hs[nb+nd][i];
      #pragma unroll
      for (int ii = 0; ii < 4; ++ii) {
        float4 wv = *(const float4*)(Wlin + l*16384 + (i+ii)*128 + c0);
        #pragma unroll
        for (int nd = 0; nd < 8; ++nd) {
          a2[nd][0] += av[nd][ii]*wv.x;
          a2[nd][1] += av[nd][ii]*wv.y;
          a2[nd][2] += av[nd][ii]*wv.z;
          a2[nd][3] += av[nd][ii]*wv.w;
        }
      }
    }
    __syncthreads();
    #pragma unroll
    for (int nd = 0; nd < 8; ++nd)
      *(float4*)&hs[nb+nd][c0] = make_float4(
          fmaxf(a2[nd][0],0.f), fmaxf(a2[nd][1],0.f),
          fmaxf(a2[nd][2],0.f), fmaxf(a2[nd][3],0.f));
    __syncthreads();
  }

  if (t < 128) {
    int c = t;
    float accm = 0.f; int gprev = -1;
    for (int nn = 0; nn < HD_NODES; ++nn) {
      int n = n0 + nn;
      if (n >= N) break;
      int g = bseg[n];
      if (g != gprev) {
        if (gprev >= 0) atomicAdd(&m[gprev*128 + c], accm);
        accm = 0.f; gprev = g;
      }
      accm += (float)outdeg[n]*hs[nn][c];
    }
    if (gprev >= 0) atomicAdd(&m[gprev*128 + c], accm);
  } else if (t == 128) {
    float a = 0.f; int gp = -1;
    for (int nn = 0; nn < HD_NODES; ++nn) {
      int n = n0 + nn;
      if (n >= N) break;
      int g = bseg[n];
      if (g != gp) {
        if (gp >= 0) atomicAdd(&cg[gp], a);
        a = 0.f; gp = g;
      }
      a += (float)outdeg[n];
    }
    if (gp >= 0) atomicAdd(&cg[gp], a);
  }
}

// ---- final: softmax((m/cg) @ Wout + bout) ----
__global__ void k_out(const float* __restrict__ m, const float* __restrict__ cg,
                      const float* __restrict__ Wout, const float* __restrict__ bout,
                      float* __restrict__ out)
{
  int g = threadIdx.x;
  if (g >= NG) return;
  float inv = 1.f / fmaxf(cg[g], 1.f);
  float v[9];
  #pragma unroll
  for (int j = 0; j < 9; ++j) {
    float a = 0.f;
    for (int i = 0; i < 128; ++i) a += m[g*128 + i]*Wout[i*9 + j];
    v[j] = a*inv + bout[j];
  }
  float mxv = v[0];
  #pragma unroll
  for (int j = 1; j < 9; ++j) mxv = fmaxf(mxv, v[j]);
  float sum = 0.f;
  #pragma unroll
  for (int j = 0; j < 9; ++j) { v[j] = expf(v[j] - mxv); sum += v[j]; }
  #pragma unroll
  for (int j = 0; j < 9; ++j) out[g*9 + j] = v[j]/sum;
}

extern "C" void kernel_launch(void* const* d_in, const int* in_sizes, int n_in,
                              void* d_out, int out_size, void* d_ws, size_t ws_size,
                              hipStream_t stream) {
  (void)in_sizes; (void)n_in; (void)out_size; (void)ws_size;
  const float* x_scalars = (const float*)d_in[0];
  const float* edge_vec  = (const float*)d_in[1];
  const float* et0_W0    = (const float*)d_in[2];
  const float* et0_W1    = (const float*)d_in[3];
  const float* et0_W2    = (const float*)d_in[4];
  const float* et0_Wd    = (const float*)d_in[5];
  const float* h_W0      = (const float*)d_in[6];
  const float* h_W1      = (const float*)d_in[7];
  const float* h_W2      = (const float*)d_in[8];
  const float* h_Wd      = (const float*)d_in[9];
  const float* Wol       = (const float*)d_in[10];
  const float* Wlin      = (const float*)d_in[11];
  const float* blin      = (const float*)d_in[12];
  const float* Wout      = (const float*)d_in[13];
  const float* bout      = (const float*)d_in[14];
  const int*   esrc      = (const int*)d_in[15];
  const int*   edst      = (const int*)d_in[16];
  const int*   bseg      = (const int*)d_in[17];

  const int N = NN, E = NE;

  char* w = (char*)d_ws;
  auto alloc = [&](size_t nbytes) {
    char* p = w;
    w += (nbytes + 255) & ~(size_t)255;
    return p;
  };
  int*   indeg   = (int*)  alloc((size_t)N*4);
  int*   outdeg  = (int*)  alloc((size_t)N*4);
  int*   cursor  = (int*)  alloc((size_t)N*4);
  int*   rowptr  = (int*)  alloc((size_t)(N+1)*4);
  int2*  csr     = (int2*) alloc((size_t)E*8);
  int*   csr_dst = (int*)  alloc((size_t)E*4);
  float* svd0    = (float*)alloc((size_t)N*18*4);
  float* stA     = (float*)alloc((size_t)N*72*4);
  float* stB     = (float*)alloc((size_t)N*72*4);
  float* qt      = (float*)alloc((size_t)N*FSTRIDE*4);
  float* kf      = (float*)alloc((size_t)N*FSTRIDE*4);
  float* vf      = (float*)alloc((size_t)N*FSTRIDE*4);
  float* elog    = (float*)alloc((size_t)E*4);
  float* mpool   = (float*)alloc((size_t)NG*128*4);
  float* cgp     = (float*)alloc((size_t)NG*4);

  hipMemsetAsync(indeg,   0, (size_t)N*4, stream);
  hipMemsetAsync(outdeg,  0, (size_t)N*4, stream);
  hipMemsetAsync(cursor,  0, (size_t)N*4, stream);
  hipMemsetAsync(mpool,   0, (size_t)NG*128*4, stream);
  hipMemsetAsync(cgp,     0, (size_t)NG*4, stream);

  const int TB = 256;
  const int gE = (E + TB - 1) / TB;
  const int gN = (N + TB - 1) / TB;
  const int gGA = (N + GA_NODES - 1) / GA_NODES;
  const int gHD = (N + HD_NODES - 1) / HD_NODES;

  // CSR build, then sh gather + init
  k_count<<<gE, TB, 0, stream>>>(esrc, edst, indeg, outdeg, E);
  k_prefix<<<1, 1024, 0, stream>>>(indeg, rowptr, N);
  k_fill<<<gE, TB, 0, stream>>>(esrc, edst, rowptr, cursor, csr, E);
  k_init_svd0<<<gN, TB, 0, stream>>>(x_scalars, edge_vec, csr, rowptr, svd0, N);

  // csr_dst (dst per sorted slot) for the logit kernel: derive from rowptr
  // cheap: reuse k_fill's info by filling from rowptr runs
  {
    // build csr_dst with a tiny kernel: one thread per node writes its run
    // (embedded lambda-style kernel not possible; do it in k_init_dst below)
  }
  // ---- build csr_dst ----
  struct Launcher {};
  // separate kernel defined below via function pointer style is not possible;
  // use a dedicated global kernel:
  extern __global__ void k_dstfill(const int* __restrict__, int* __restrict__, int);
  k_dstfill<<<gN, TB, 0, stream>>>(rowptr, csr_dst, N);

  // ---- et0 layer (no residual) ----
  k_node_feats<10,1><<<gN, TB, 0, stream>>>(svd0, et0_W0, et0_W1, et0_W2, et0_Wd, qt, kf, vf, N);
  k_edge_logit2<<<gE, TB, 0, stream>>>(qt, kf, csr, csr_dst, elog, E);
  k_attn_gather<<<gGA, 576, 0, stream>>>(elog, vf, csr, rowptr, nullptr, stA, N);

  // ---- 2 hidden layers with residual ----
  float* cur = stA; float* oth = stB;
  for (int l = 0; l < 2; ++l) {
    k_node_feats<8,8><<<gN, TB, 0, stream>>>(cur, h_W0 + l*192, h_W1 + l*192,
                                             h_W2 + l*192, h_Wd + l*192, qt, kf, vf, N);
    k_edge_logit2<<<gE, TB, 0, stream>>>(qt, kf, csr, csr_dst, elog, E);
    k_attn_gather<<<gGA, 576, 0, stream>>>(elog, vf, csr, rowptr, cur, oth, N);
    float* t = cur; cur = oth; oth = t;
  }

  // ---- fused MLP head + group pooling ----
  k_head<<<gHD, 256, 0, stream>>>(cur, Wol, Wlin, blin, outdeg, bseg, mpool, cgp, N);
  k_out<<<1, 64, 0, stream>>>(mpool, cgp, Wout, bout, (float*)d_out);
}

// ---- csr_dst fill: one thread per node writes its slot-run ----
__global__ void k_dstfill(const int* __restrict__ rowptr, int* __restrict__ csr_dst, int N)
{
  int n = blockIdx.x*blockDim.x + threadIdx.x;
  if (n >= N) return;
  int b = rowptr[n], e2 = rowptr[n+1];
  for (int s = b; s < e2; ++s) csr_dst[s] = n;
}

// Round 6
// 662.223 us; speedup vs baseline: 1.3242x; 1.2117x over previous
//
#include <hip/hip_runtime.h>
#include <math.h>

#define NN 50000
#define NE 800000
#define NG 64
#define QSTRIDE 80    // qt row stride (floats): 320 B, 64B-aligned
#define KVSTRIDE 160  // kv row stride (floats): 640 B; record = 144 floats (K||V)

// ---- CSR build: count ----
__global__ void k_count(const int* __restrict__ esrc, const int* __restrict__ edst,
                        int* __restrict__ indeg, int* __restrict__ outdeg, int E)
{
  int e = blockIdx.x*blockDim.x + threadIdx.x;
  if (e >= E) return;
  atomicAdd(indeg + edst[e], 1);
  atomicAdd(outdeg + esrc[e], 1);
}

// ---- CSR build: single-block exclusive prefix scan over N=50000 ----
__global__ void __launch_bounds__(1024) k_prefix(const int* __restrict__ indeg,
                                                 int* __restrict__ rowptr, int N)
{
  __shared__ int tot[1024];
  int t = threadIdx.x;
  int chunk = (N + 1023) / 1024;
  int lo = t*chunk, hi = lo + chunk; if (hi > N) hi = N; if (lo > N) lo = N;
  int s = 0;
  for (int i = lo; i < hi; ++i) s += indeg[i];
  tot[t] = s;
  __syncthreads();
  for (int off = 1; off < 1024; off <<= 1) {
    int v = 0;
    if (t >= off) v = tot[t-off];
    __syncthreads();
    if (t >= off) tot[t] += v;
    __syncthreads();
  }
  int base = (t == 0) ? 0 : tot[t-1];
  for (int i = lo; i < hi; ++i) {
    rowptr[i] = base;
    base += indeg[i];
  }
  if (t == 1023) rowptr[N] = tot[1023];
}

// ---- CSR build: fill; single int2{src,eid} 8B write per edge ----
__global__ void k_fill(const int* __restrict__ esrc, const int* __restrict__ edst,
                       const int* __restrict__ rowptr, int* __restrict__ cursor,
                       int2* __restrict__ csr, int E)
{
  int e = blockIdx.x*blockDim.x + threadIdx.x;
  if (e >= E) return;
  int d = edst[e];
  int slot = rowptr[d] + atomicAdd(cursor + d, 1);
  csr[slot] = make_int2(esrc[e], e);
}

// ---- init: gather sh over CSR run + concat scalars -> svd0 [N,18] ----
__global__ void k_init_svd0(const float* __restrict__ xs,
                            const float* __restrict__ evec,
                            const int2* __restrict__ csr,
                            const int* __restrict__ rowptr,
                            float* __restrict__ svd0, int N)
{
  int n = blockIdx.x*blockDim.x + threadIdx.x;
  if (n >= N) return;
  int b = rowptr[n], e2 = rowptr[n+1];
  float acc[9];
  #pragma unroll
  for (int j = 0; j < 9; ++j) acc[j] = 0.f;
  const float s3  = 1.7320508075688772f;
  const float s15 = 3.872983346207417f;
  const float s5  = 2.23606797749979f;
  for (int s = b; s < e2; ++s) {
    int eid = csr[s].y;
    float vx = evec[3*eid+0], vy = evec[3*eid+1], vz = evec[3*eid+2];
    float r = sqrtf(vx*vx + vy*vy + vz*vz + 1e-12f);
    float x = vx / r, y = vy / r, z = vz / r;
    acc[0] += 1.f;
    acc[1] += s3*x; acc[2] += s3*y; acc[3] += s3*z;
    acc[4] += s15*x*z;
    acc[5] += s15*x*y;
    acc[6] += s5*(y*y - 0.5f*(x*x + z*z));
    acc[7] += s15*y*z;
    acc[8] += 0.5f*s15*(z*z - x*x);
  }
  int dg = e2 - b;
  float inv = 1.f / (float)(dg > 1 ? dg : 1);
  float* o = svd0 + (size_t)n*18;
  const float* xrow = xs + (size_t)n*9;
  #pragma unroll
  for (int j = 0; j < 9; ++j) o[j] = xrow[j];
  #pragma unroll
  for (int j = 0; j < 9; ++j) o[9+j] = acc[j]*inv;
}

// ---- kernel A: node-level q/k/v features; q pre-contracted with Wd ----
// qt rows: QSTRIDE floats; kv rows: KVSTRIDE floats, K at [0,72), V at [72,144)
template<int CS, int CV>
__global__ void __launch_bounds__(256) k_node_feats(
    const float* __restrict__ in,
    const float* __restrict__ W0,  // [3,CS,8]
    const float* __restrict__ W1,  // [3,CV,8]
    const float* __restrict__ W2,  // [3,CV,8]
    const float* __restrict__ Wd,  // [3,8,8]
    float* __restrict__ qt,
    float* __restrict__ kv,
    int N)
{
  int n = blockIdx.x*blockDim.x + threadIdx.x;
  if (n >= N) return;
  const float* x = in + (size_t)n*(CS + 8*CV);
  float s_in[CS];
  float v_in[CV][3];
  float d_in[CV][5];
  #pragma unroll
  for (int i = 0; i < CS; ++i) s_in[i] = x[i];
  #pragma unroll
  for (int i = 0; i < CV; ++i)
    #pragma unroll
    for (int m = 0; m < 3; ++m) v_in[i][m] = x[CS + i*3 + m];
  #pragma unroll
  for (int i = 0; i < CV; ++i)
    #pragma unroll
    for (int m = 0; m < 5; ++m) d_in[i][m] = x[CS + 3*CV + i*5 + m];

  const float inv_s3 = 0.5773502691896258f;
  const float inv_s5 = 0.4472135954999579f;

  #pragma unroll
  for (int t = 0; t < 3; ++t) {
    float ss[8];
    float vv[8][3];
    float dd[8][5];
    #pragma unroll
    for (int c = 0; c < 8; ++c) {
      float a = 0.f;
      #pragma unroll
      for (int i = 0; i < CS; ++i) a += s_in[i]*W0[t*CS*8 + i*8 + c];
      ss[c] = a;
    }
    #pragma unroll
    for (int c = 0; c < 8; ++c)
      #pragma unroll
      for (int m = 0; m < 3; ++m) {
        float a = 0.f;
        #pragma unroll
        for (int i = 0; i < CV; ++i) a += v_in[i][m]*W1[t*CV*8 + i*8 + c];
        vv[c][m] = a;
      }
    #pragma unroll
    for (int c = 0; c < 8; ++c)
      #pragma unroll
      for (int m = 0; m < 5; ++m) {
        float a = 0.f;
        #pragma unroll
        for (int i = 0; i < CV; ++i) a += d_in[i][m]*W2[t*CV*8 + i*8 + c];
        dd[c][m] = a;
      }

    if (t == 0) {
      float* q = qt + (size_t)n*QSTRIDE;
      #pragma unroll
      for (int dp = 0; dp < 8; ++dp) {
        float a = 0.f;
        #pragma unroll
        for (int c = 0; c < 8; ++c) a += ss[c]*Wd[0*64 + c*8 + dp];
        q[dp] = a;
      }
      #pragma unroll
      for (int dp = 0; dp < 8; ++dp)
        #pragma unroll
        for (int m = 0; m < 3; ++m) {
          float a = 0.f;
          #pragma unroll
          for (int c = 0; c < 8; ++c) a += vv[c][m]*Wd[1*64 + c*8 + dp];
          q[8 + dp*3 + m] = a*inv_s3;
        }
      #pragma unroll
      for (int dp = 0; dp < 8; ++dp)
        #pragma unroll
        for (int m = 0; m < 5; ++m) {
          float a = 0.f;
          #pragma unroll
          for (int c = 0; c < 8; ++c) a += dd[c][m]*Wd[2*64 + c*8 + dp];
          q[32 + dp*5 + m] = a*inv_s5;
        }
    } else {
      float* o = kv + (size_t)n*KVSTRIDE + (t == 1 ? 0 : 72);
      #pragma unroll
      for (int c = 0; c < 8; ++c) o[c] = ss[c];
      #pragma unroll
      for (int c = 0; c < 8; ++c)
        #pragma unroll
        for (int m = 0; m < 3; ++m) o[8 + c*3 + m] = vv[c][m];
      #pragma unroll
      for (int c = 0; c < 8; ++c)
        #pragma unroll
        for (int m = 0; m < 5; ++m) o[32 + c*5 + m] = dd[c][m];
    }
  }
}

// ---- fused attention: one pass/edge, half-wave (32 lanes) per node ----
// online-sqrt softmax: w_i = exp((l_i-m)/2)/sqrt(Z), Z = sum exp(l_j-m)
#define AT2_NPB 8
__global__ void __launch_bounds__(256) k_attn2(
    const float* __restrict__ qt,
    const float* __restrict__ kv,
    const int2* __restrict__ csr,
    const int* __restrict__ rowptr,
    const float* __restrict__ base,   // residual input or nullptr
    float* __restrict__ out, int N)
{
  int t = threadIdx.x;
  int half = t >> 5;       // 0..7
  int lane = t & 31;       // 0..31
  int n = blockIdx.x*AT2_NPB + half;
  if (n >= N) return;

  float4 qv = make_float4(0.f,0.f,0.f,0.f);
  if (lane < 18) qv = *(const float4*)(qt + (size_t)n*QSTRIDE + lane*4);

  int b = rowptr[n], e2 = rowptr[n+1];
  float m = -3.4e38f, Z = 0.f;
  float4 A = make_float4(0.f,0.f,0.f,0.f);

  for (int s = b; s < e2; ++s) {
    int src = csr[s].x;
    const float4* kvp = (const float4*)(kv + (size_t)src*KVSTRIDE);
    float4 kk = make_float4(0.f,0.f,0.f,0.f);
    float4 vv = make_float4(0.f,0.f,0.f,0.f);
    if (lane < 18) { kk = kvp[lane]; vv = kvp[18 + lane]; }
    float part = qv.x*kk.x + qv.y*kk.y + qv.z*kk.z + qv.w*kk.w;
    #pragma unroll
    for (int off = 1; off < 32; off <<= 1)
      part += __shfl_xor(part, off, 32);
    float l = part;                       // logit, broadcast to all 32 lanes
    if (l > m) {
      float r = expf((m - l)*0.5f);       // first edge: m=-inf -> r=0
      Z = Z*r*r + 1.f;
      A.x = A.x*r + vv.x; A.y = A.y*r + vv.y;
      A.z = A.z*r + vv.z; A.w = A.w*r + vv.w;
      m = l;
    } else {
      float eh = expf((l - m)*0.5f);
      Z += eh*eh;
      A.x += eh*vv.x; A.y += eh*vv.y;
      A.z += eh*vv.z; A.w += eh*vv.w;
    }
  }

  float rz = (Z > 0.f) ? rsqrtf(Z) : 0.f;
  float4 o = make_float4(A.x*rz, A.y*rz, A.z*rz, A.w*rz);
  if (lane < 18) {
    if (base) {
      float4 bb = *(const float4*)(base + (size_t)n*72 + lane*4);
      o.x += bb.x; o.y += bb.y; o.z += bb.z; o.w += bb.w;
    }
    *(float4*)(out + (size_t)n*72 + lane*4) = o;
  }
}

// ---- fused head: 64 nodes/block, 512 threads, register-tiled GEMM ----
#define HD_NODES 64
__global__ void __launch_bounds__(512) k_head(
    const float* __restrict__ svd,   // [N,72], s = first 8
    const float* __restrict__ Wol,   // [8,128]
    const float* __restrict__ Wlin,  // [2,128,128]
    const float* __restrict__ blin,  // [2,128]
    const int* __restrict__ outdeg,
    const int* __restrict__ bseg,
    float* __restrict__ m,           // [G,128] atomic
    float* __restrict__ cg,          // [G] atomic
    int N)
{
  __shared__ float hs[HD_NODES][128];   // 32 KB
  __shared__ float ssm[HD_NODES][8];    // 2 KB
  __shared__ float nrm_p[HD_NODES][33]; // 8.4 KB
  __shared__ float rinv[HD_NODES];
  int t = threadIdx.x;
  int n0 = blockIdx.x*HD_NODES;
  int tc = t & 31, tr = t >> 5;   // 32 col-groups x 16 node-groups
  int c0 = tc*4;
  int nb = tr*4;

  { // load s: 8 threads/node, one float each
    int node = t >> 3, i = t & 7;
    int gn = n0 + node;
    ssm[node][i] = (gn < N) ? svd[(size_t)gn*72 + i] : 0.f;
  }
  __syncthreads();

  // L1: h = s @ Wol (8 -> 128), pre-norm
  float acc[4][4];
  #pragma unroll
  for (int nd = 0; nd < 4; ++nd)
    #pragma unroll
    for (int cc = 0; cc < 4; ++cc) acc[nd][cc] = 0.f;
  #pragma unroll
  for (int i = 0; i < 8; ++i) {
    float4 wv = *(const float4*)(Wol + i*128 + c0);
    #pragma unroll
    for (int nd = 0; nd < 4; ++nd) {
      float a = ssm[nb+nd][i];
      acc[nd][0] += a*wv.x; acc[nd][1] += a*wv.y;
      acc[nd][2] += a*wv.z; acc[nd][3] += a*wv.w;
    }
  }
  #pragma unroll
  for (int nd = 0; nd < 4; ++nd) {
    *(float4*)&hs[nb+nd][c0] = make_float4(acc[nd][0],acc[nd][1],acc[nd][2],acc[nd][3]);
    nrm_p[nb+nd][tc] = acc[nd][0]*acc[nd][0] + acc[nd][1]*acc[nd][1]
                     + acc[nd][2]*acc[nd][2] + acc[nd][3]*acc[nd][3];
  }
  __syncthreads();
  if (t < HD_NODES) {
    float sq = 0.f;
    #pragma unroll
    for (int k = 0; k < 32; ++k) sq += nrm_p[t][k];
    rinv[t] = 1.f / fmaxf(sqrtf(sq), 1e-12f);
  }
  __syncthreads();
  #pragma unroll
  for (int k = 0; k < 16; ++k) {
    int idx = t + k*512;
    int node = idx >> 7, c = idx & 127;
    hs[node][c] = fmaxf(hs[node][c]*rinv[node], 0.f);
  }
  __syncthreads();

  for (int l = 0; l < 2; ++l) {
    float4 bv = *(const float4*)(blin + l*128 + c0);
    float a2[4][4];
    #pragma unroll
    for (int nd = 0; nd < 4; ++nd) {
      a2[nd][0]=bv.x; a2[nd][1]=bv.y; a2[nd][2]=bv.z; a2[nd][3]=bv.w;
    }
    for (int i = 0; i < 128; i += 4) {
      float av[4][4];
      #pragma unroll
      for (int nd = 0; nd < 4; ++nd)
        *(float4*)av[nd] = *(const float4*)&hs[nb+nd][i];
      #pragma unroll
      for (int ii = 0; ii < 4; ++ii) {
        float4 wv = *(const float4*)(Wlin + l*16384 + (i+ii)*128 + c0);
        #pragma unroll
        for (int nd = 0; nd < 4; ++nd) {
          a2[nd][0] += av[nd][ii]*wv.x;
          a2[nd][1] += av[nd][ii]*wv.y;
          a2[nd][2] += av[nd][ii]*wv.z;
          a2[nd][3] += av[nd][ii]*wv.w;
        }
      }
    }
    __syncthreads();
    #pragma unroll
    for (int nd = 0; nd < 4; ++nd)
      *(float4*)&hs[nb+nd][c0] = make_float4(
          fmaxf(a2[nd][0],0.f), fmaxf(a2[nd][1],0.f),
          fmaxf(a2[nd][2],0.f), fmaxf(a2[nd][3],0.f));
    __syncthreads();
  }

  if (t < 128) {
    int c = t;
    float accm = 0.f; int gprev = -1;
    for (int nn = 0; nn < HD_NODES; ++nn) {
      int n = n0 + nn;
      if (n >= N) break;
      int g = bseg[n];
      if (g != gprev) {
        if (gprev >= 0) atomicAdd(&m[gprev*128 + c], accm);
        accm = 0.f; gprev = g;
      }
      accm += (float)outdeg[n]*hs[nn][c];
    }
    if (gprev >= 0) atomicAdd(&m[gprev*128 + c], accm);
  } else if (t == 128) {
    float a = 0.f; int gp = -1;
    for (int nn = 0; nn < HD_NODES; ++nn) {
      int n = n0 + nn;
      if (n >= N) break;
      int g = bseg[n];
      if (g != gp) {
        if (gp >= 0) atomicAdd(&cg[gp], a);
        a = 0.f; gp = g;
      }
      a += (float)outdeg[n];
    }
    if (gp >= 0) atomicAdd(&cg[gp], a);
  }
}

// ---- final: softmax((m/cg) @ Wout + bout) ----
__global__ void k_out(const float* __restrict__ m, const float* __restrict__ cg,
                      const float* __restrict__ Wout, const float* __restrict__ bout,
                      float* __restrict__ out)
{
  int g = threadIdx.x;
  if (g >= NG) return;
  float inv = 1.f / fmaxf(cg[g], 1.f);
  float v[9];
  #pragma unroll
  for (int j = 0; j < 9; ++j) {
    float a = 0.f;
    for (int i = 0; i < 128; ++i) a += m[g*128 + i]*Wout[i*9 + j];
    v[j] = a*inv + bout[j];
  }
  float mxv = v[0];
  #pragma unroll
  for (int j = 1; j < 9; ++j) mxv = fmaxf(mxv, v[j]);
  float sum = 0.f;
  #pragma unroll
  for (int j = 0; j < 9; ++j) { v[j] = expf(v[j] - mxv); sum += v[j]; }
  #pragma unroll
  for (int j = 0; j < 9; ++j) out[g*9 + j] = v[j]/sum;
}

extern "C" void kernel_launch(void* const* d_in, const int* in_sizes, int n_in,
                              void* d_out, int out_size, void* d_ws, size_t ws_size,
                              hipStream_t stream) {
  (void)in_sizes; (void)n_in; (void)out_size; (void)ws_size;
  const float* x_scalars = (const float*)d_in[0];
  const float* edge_vec  = (const float*)d_in[1];
  const float* et0_W0    = (const float*)d_in[2];
  const float* et0_W1    = (const float*)d_in[3];
  const float* et0_W2    = (const float*)d_in[4];
  const float* et0_Wd    = (const float*)d_in[5];
  const float* h_W0      = (const float*)d_in[6];
  const float* h_W1      = (const float*)d_in[7];
  const float* h_W2      = (const float*)d_in[8];
  const float* h_Wd      = (const float*)d_in[9];
  const float* Wol       = (const float*)d_in[10];
  const float* Wlin      = (const float*)d_in[11];
  const float* blin      = (const float*)d_in[12];
  const float* Wout      = (const float*)d_in[13];
  const float* bout      = (const float*)d_in[14];
  const int*   esrc      = (const int*)d_in[15];
  const int*   edst      = (const int*)d_in[16];
  const int*   bseg      = (const int*)d_in[17];

  const int N = NN, E = NE;

  char* w = (char*)d_ws;
  auto alloc = [&](size_t nbytes) {
    char* p = w;
    w += (nbytes + 255) & ~(size_t)255;
    return p;
  };
  int*   indeg   = (int*)  alloc((size_t)N*4);
  int*   outdeg  = (int*)  alloc((size_t)N*4);
  int*   cursor  = (int*)  alloc((size_t)N*4);
  int*   rowptr  = (int*)  alloc((size_t)(N+1)*4);
  int2*  csr     = (int2*) alloc((size_t)E*8);
  float* svd0    = (float*)alloc((size_t)N*18*4);
  float* stA     = (float*)alloc((size_t)N*72*4);
  float* stB     = (float*)alloc((size_t)N*72*4);
  float* qt      = (float*)alloc((size_t)N*QSTRIDE*4);
  float* kv      = (float*)alloc((size_t)N*KVSTRIDE*4);
  float* mpool   = (float*)alloc((size_t)NG*128*4);
  float* cgp     = (float*)alloc((size_t)NG*4);

  hipMemsetAsync(indeg,   0, (size_t)N*4, stream);
  hipMemsetAsync(outdeg,  0, (size_t)N*4, stream);
  hipMemsetAsync(cursor,  0, (size_t)N*4, stream);
  hipMemsetAsync(mpool,   0, (size_t)NG*128*4, stream);
  hipMemsetAsync(cgp,     0, (size_t)NG*4, stream);

  const int TB = 256;
  const int gE  = (E + TB - 1) / TB;
  const int gN  = (N + TB - 1) / TB;
  const int gA2 = (N + AT2_NPB - 1) / AT2_NPB;
  const int gHD = (N + HD_NODES - 1) / HD_NODES;

  // CSR build, then sh gather + init
  k_count<<<gE, TB, 0, stream>>>(esrc, edst, indeg, outdeg, E);
  k_prefix<<<1, 1024, 0, stream>>>(indeg, rowptr, N);
  k_fill<<<gE, TB, 0, stream>>>(esrc, edst, rowptr, cursor, csr, E);
  k_init_svd0<<<gN, TB, 0, stream>>>(x_scalars, edge_vec, csr, rowptr, svd0, N);

  // ---- et0 layer (no residual) ----
  k_node_feats<10,1><<<gN, TB, 0, stream>>>(svd0, et0_W0, et0_W1, et0_W2, et0_Wd, qt, kv, N);
  k_attn2<<<gA2, 256, 0, stream>>>(qt, kv, csr, rowptr, nullptr, stA, N);

  // ---- 2 hidden layers with residual ----
  float* cur = stA; float* oth = stB;
  for (int l = 0; l < 2; ++l) {
    k_node_feats<8,8><<<gN, TB, 0, stream>>>(cur, h_W0 + l*192, h_W1 + l*192,
                                             h_W2 + l*192, h_Wd + l*192, qt, kv, N);
    k_attn2<<<gA2, 256, 0, stream>>>(qt, kv, csr, rowptr, cur, oth, N);
    float* t = cur; cur = oth; oth = t;
  }

  // ---- fused MLP head + group pooling ----
  k_head<<<gHD, 512, 0, stream>>>(cur, Wol, Wlin, blin, outdeg, bseg, mpool, cgp, N);
  k_out<<<1, 64, 0, stream>>>(mpool, cgp, Wout, bout, (float*)d_out);
}

// Round 7
// 612.356 us; speedup vs baseline: 1.4321x; 1.0814x over previous
//
#include <hip/hip_runtime.h>
#include <math.h>

#define NN 50000
#define NE 800000
#define NG 64
#define QSTRIDE 80    // qt row stride (floats): 320 B
#define KVSTRIDE 144  // kv row: 144 floats = 576 B = 9 full 64B lines, tight-packed

// ---- CSR build: count ----
__global__ void k_count(const int* __restrict__ esrc, const int* __restrict__ edst,
                        int* __restrict__ indeg, int* __restrict__ outdeg, int E)
{
  int e = blockIdx.x*blockDim.x + threadIdx.x;
  if (e >= E) return;
  atomicAdd(indeg + edst[e], 1);
  atomicAdd(outdeg + esrc[e], 1);
}

// ---- CSR build: single-block exclusive prefix scan over N=50000 ----
__global__ void __launch_bounds__(1024) k_prefix(const int* __restrict__ indeg,
                                                 int* __restrict__ rowptr, int N)
{
  __shared__ int tot[1024];
  int t = threadIdx.x;
  int chunk = (N + 1023) / 1024;
  int lo = t*chunk, hi = lo + chunk; if (hi > N) hi = N; if (lo > N) lo = N;
  int s = 0;
  for (int i = lo; i < hi; ++i) s += indeg[i];
  tot[t] = s;
  __syncthreads();
  for (int off = 1; off < 1024; off <<= 1) {
    int v = 0;
    if (t >= off) v = tot[t-off];
    __syncthreads();
    if (t >= off) tot[t] += v;
    __syncthreads();
  }
  int base = (t == 0) ? 0 : tot[t-1];
  for (int i = lo; i < hi; ++i) {
    rowptr[i] = base;
    base += indeg[i];
  }
  if (t == 1023) rowptr[N] = tot[1023];
}

// ---- CSR build: fill; single int2{src,eid} 8B write per edge ----
__global__ void k_fill(const int* __restrict__ esrc, const int* __restrict__ edst,
                       const int* __restrict__ rowptr, int* __restrict__ cursor,
                       int2* __restrict__ csr, int E)
{
  int e = blockIdx.x*blockDim.x + threadIdx.x;
  if (e >= E) return;
  int d = edst[e];
  int slot = rowptr[d] + atomicAdd(cursor + d, 1);
  csr[slot] = make_int2(esrc[e], e);
}

// ---- kernel A: node q/k/v features; q pre-contracted with Wd.
// INIT=true: et0 layer — input is xs[N,9] + sh gathered inline from evec/csr.
// INIT=false: hidden layer — input is state rows [N,72] (s8, v8x3, d8x5).
template<int CS, int CV, bool INIT>
__global__ void __launch_bounds__(256) k_node_feats(
    const float* __restrict__ in,
    const float* __restrict__ evec,
    const int2* __restrict__ csr,
    const int* __restrict__ rowptr,
    const float* __restrict__ W0,  // [3,CS,8]
    const float* __restrict__ W1,  // [3,CV,8]
    const float* __restrict__ W2,  // [3,CV,8]
    const float* __restrict__ Wd,  // [3,8,8]
    float* __restrict__ qt,
    float* __restrict__ kv,
    int N)
{
  int n = blockIdx.x*blockDim.x + threadIdx.x;
  if (n >= N) return;
  float s_in[CS];
  float v_in[CV][3];
  float d_in[CV][5];

  if constexpr (INIT) {
    // gather spherical harmonics over this node's CSR run
    int b = rowptr[n], e2 = rowptr[n+1];
    float acc[9];
    #pragma unroll
    for (int j = 0; j < 9; ++j) acc[j] = 0.f;
    const float s3  = 1.7320508075688772f;
    const float s15 = 3.872983346207417f;
    const float s5  = 2.23606797749979f;
    for (int s = b; s < e2; ++s) {
      int eid = csr[s].y;
      float vx = evec[3*eid+0], vy = evec[3*eid+1], vz = evec[3*eid+2];
      float r = sqrtf(vx*vx + vy*vy + vz*vz + 1e-12f);
      float x = vx / r, y = vy / r, z = vz / r;
      acc[0] += 1.f;
      acc[1] += s3*x; acc[2] += s3*y; acc[3] += s3*z;
      acc[4] += s15*x*z;
      acc[5] += s15*x*y;
      acc[6] += s5*(y*y - 0.5f*(x*x + z*z));
      acc[7] += s15*y*z;
      acc[8] += 0.5f*s15*(z*z - x*x);
    }
    int dg = e2 - b;
    float inv = 1.f / (float)(dg > 1 ? dg : 1);
    #pragma unroll
    for (int j = 0; j < 9; ++j) s_in[j] = in[(size_t)n*9 + j];
    s_in[9] = acc[0]*inv;
    #pragma unroll
    for (int m = 0; m < 3; ++m) v_in[0][m] = acc[1+m]*inv;
    #pragma unroll
    for (int m = 0; m < 5; ++m) d_in[0][m] = acc[4+m]*inv;
  } else {
    const float* x = in + (size_t)n*72;
    #pragma unroll
    for (int i = 0; i < CS; ++i) s_in[i] = x[i];
    #pragma unroll
    for (int i = 0; i < CV; ++i)
      #pragma unroll
      for (int m = 0; m < 3; ++m) v_in[i][m] = x[CS + i*3 + m];
    #pragma unroll
    for (int i = 0; i < CV; ++i)
      #pragma unroll
      for (int m = 0; m < 5; ++m) d_in[i][m] = x[CS + 3*CV + i*5 + m];
  }

  const float inv_s3 = 0.5773502691896258f;
  const float inv_s5 = 0.4472135954999579f;

  #pragma unroll
  for (int t = 0; t < 3; ++t) {
    float ss[8];
    float vv[8][3];
    float dd[8][5];
    #pragma unroll
    for (int c = 0; c < 8; ++c) {
      float a = 0.f;
      #pragma unroll
      for (int i = 0; i < CS; ++i) a += s_in[i]*W0[t*CS*8 + i*8 + c];
      ss[c] = a;
    }
    #pragma unroll
    for (int c = 0; c < 8; ++c)
      #pragma unroll
      for (int m = 0; m < 3; ++m) {
        float a = 0.f;
        #pragma unroll
        for (int i = 0; i < CV; ++i) a += v_in[i][m]*W1[t*CV*8 + i*8 + c];
        vv[c][m] = a;
      }
    #pragma unroll
    for (int c = 0; c < 8; ++c)
      #pragma unroll
      for (int m = 0; m < 5; ++m) {
        float a = 0.f;
        #pragma unroll
        for (int i = 0; i < CV; ++i) a += d_in[i][m]*W2[t*CV*8 + i*8 + c];
        dd[c][m] = a;
      }

    if (t == 0) {
      float* q = qt + (size_t)n*QSTRIDE;
      #pragma unroll
      for (int dp = 0; dp < 8; ++dp) {
        float a = 0.f;
        #pragma unroll
        for (int c = 0; c < 8; ++c) a += ss[c]*Wd[0*64 + c*8 + dp];
        q[dp] = a;
      }
      #pragma unroll
      for (int dp = 0; dp < 8; ++dp)
        #pragma unroll
        for (int m = 0; m < 3; ++m) {
          float a = 0.f;
          #pragma unroll
          for (int c = 0; c < 8; ++c) a += vv[c][m]*Wd[1*64 + c*8 + dp];
          q[8 + dp*3 + m] = a*inv_s3;
        }
      #pragma unroll
      for (int dp = 0; dp < 8; ++dp)
        #pragma unroll
        for (int m = 0; m < 5; ++m) {
          float a = 0.f;
          #pragma unroll
          for (int c = 0; c < 8; ++c) a += dd[c][m]*Wd[2*64 + c*8 + dp];
          q[32 + dp*5 + m] = a*inv_s5;
        }
    } else {
      float* o = kv + (size_t)n*KVSTRIDE + (t == 1 ? 0 : 72);
      #pragma unroll
      for (int c = 0; c < 8; ++c) o[c] = ss[c];
      #pragma unroll
      for (int c = 0; c < 8; ++c)
        #pragma unroll
        for (int m = 0; m < 3; ++m) o[8 + c*3 + m] = vv[c][m];
      #pragma unroll
      for (int c = 0; c < 8; ++c)
        #pragma unroll
        for (int m = 0; m < 5; ++m) o[32 + c*5 + m] = dd[c][m];
    }
  }
}

// ---- fused attention: one pass/edge, half-wave (32 lanes) per node ----
// raw-exp softmax (matches reference, no max subtraction):
// w_i = exp(l_i/2)/sqrt(Z), Z = sum exp(l_j). 2-way edge unroll for MLP/ILP.
#define AT2_NPB 8
__global__ void __launch_bounds__(256) k_attn2(
    const float* __restrict__ qt,
    const float* __restrict__ kv,
    const int2* __restrict__ csr,
    const int* __restrict__ rowptr,
    const float* __restrict__ base,   // residual input or nullptr
    float* __restrict__ out, int N)
{
  int t = threadIdx.x;
  int half = t >> 5;       // 0..7
  int lane = t & 31;       // 0..31
  int n = blockIdx.x*AT2_NPB + half;
  if (n >= N) return;

  float4 qv = make_float4(0.f,0.f,0.f,0.f);
  if (lane < 18) qv = *(const float4*)(qt + (size_t)n*QSTRIDE + lane*4);

  int b = rowptr[n], e2 = rowptr[n+1];
  float Z = 0.f;
  float4 A = make_float4(0.f,0.f,0.f,0.f);

  int s = b;
  for (; s + 2 <= e2; s += 2) {
    int src0 = csr[s].x, src1 = csr[s+1].x;
    const float4* p0 = (const float4*)(kv + (size_t)src0*KVSTRIDE);
    const float4* p1 = (const float4*)(kv + (size_t)src1*KVSTRIDE);
    float4 k0 = make_float4(0.f,0.f,0.f,0.f), v0 = k0, k1 = k0, v1 = k0;
    if (lane < 18) {
      k0 = p0[lane]; v0 = p0[18 + lane];
      k1 = p1[lane]; v1 = p1[18 + lane];
    }
    float d0 = qv.x*k0.x + qv.y*k0.y + qv.z*k0.z + qv.w*k0.w;
    float d1 = qv.x*k1.x + qv.y*k1.y + qv.z*k1.z + qv.w*k1.w;
    #pragma unroll
    for (int off = 1; off < 32; off <<= 1) {
      d0 += __shfl_xor(d0, off, 32);
      d1 += __shfl_xor(d1, off, 32);
    }
    float eh0 = expf(0.5f*d0);
    float eh1 = expf(0.5f*d1);
    Z += eh0*eh0 + eh1*eh1;
    A.x += eh0*v0.x + eh1*v1.x;
    A.y += eh0*v0.y + eh1*v1.y;
    A.z += eh0*v0.z + eh1*v1.z;
    A.w += eh0*v0.w + eh1*v1.w;
  }
  if (s < e2) {
    int src0 = csr[s].x;
    const float4* p0 = (const float4*)(kv + (size_t)src0*KVSTRIDE);
    float4 k0 = make_float4(0.f,0.f,0.f,0.f), v0 = k0;
    if (lane < 18) { k0 = p0[lane]; v0 = p0[18 + lane]; }
    float d0 = qv.x*k0.x + qv.y*k0.y + qv.z*k0.z + qv.w*k0.w;
    #pragma unroll
    for (int off = 1; off < 32; off <<= 1) d0 += __shfl_xor(d0, off, 32);
    float eh0 = expf(0.5f*d0);
    Z += eh0*eh0;
    A.x += eh0*v0.x; A.y += eh0*v0.y; A.z += eh0*v0.z; A.w += eh0*v0.w;
  }

  float rz = (Z > 0.f) ? rsqrtf(Z) : 0.f;
  float4 o = make_float4(A.x*rz, A.y*rz, A.z*rz, A.w*rz);
  if (lane < 18) {
    if (base) {
      float4 bb = *(const float4*)(base + (size_t)n*72 + lane*4);
      o.x += bb.x; o.y += bb.y; o.z += bb.z; o.w += bb.w;
    }
    *(float4*)(out + (size_t)n*72 + lane*4) = o;
  }
}

// ---- fused head: 64 nodes/block, 512 threads, register-tiled GEMM ----
#define HD_NODES 64
__global__ void __launch_bounds__(512) k_head(
    const float* __restrict__ svd,   // [N,72], s = first 8
    const float* __restrict__ Wol,   // [8,128]
    const float* __restrict__ Wlin,  // [2,128,128]
    const float* __restrict__ blin,  // [2,128]
    const int* __restrict__ outdeg,
    const int* __restrict__ bseg,
    float* __restrict__ m,           // [G,128] atomic
    float* __restrict__ cg,          // [G] atomic
    int N)
{
  __shared__ float hs[HD_NODES][128];   // 32 KB
  __shared__ float ssm[HD_NODES][8];    // 2 KB
  __shared__ float nrm_p[HD_NODES][33]; // 8.4 KB
  __shared__ float rinv[HD_NODES];
  int t = threadIdx.x;
  int n0 = blockIdx.x*HD_NODES;
  int tc = t & 31, tr = t >> 5;   // 32 col-groups x 16 node-groups
  int c0 = tc*4;
  int nb = tr*4;

  { // load s: 8 threads/node, one float each
    int node = t >> 3, i = t & 7;
    int gn = n0 + node;
    ssm[node][i] = (gn < N) ? svd[(size_t)gn*72 + i] : 0.f;
  }
  __syncthreads();

  float acc[4][4];
  #pragma unroll
  for (int nd = 0; nd < 4; ++nd)
    #pragma unroll
    for (int cc = 0; cc < 4; ++cc) acc[nd][cc] = 0.f;
  #pragma unroll
  for (int i = 0; i < 8; ++i) {
    float4 wv = *(const float4*)(Wol + i*128 + c0);
    #pragma unroll
    for (int nd = 0; nd < 4; ++nd) {
      float a = ssm[nb+nd][i];
      acc[nd][0] += a*wv.x; acc[nd][1] += a*wv.y;
      acc[nd][2] += a*wv.z; acc[nd][3] += a*wv.w;
    }
  }
  #pragma unroll
  for (int nd = 0; nd < 4; ++nd) {
    *(float4*)&hs[nb+nd][c0] = make_float4(acc[nd][0],acc[nd][1],acc[nd][2],acc[nd][3]);
    nrm_p[nb+nd][tc] = acc[nd][0]*acc[nd][0] + acc[nd][1]*acc[nd][1]
                     + acc[nd][2]*acc[nd][2] + acc[nd][3]*acc[nd][3];
  }
  __syncthreads();
  if (t < HD_NODES) {
    float sq = 0.f;
    #pragma unroll
    for (int k = 0; k < 32; ++k) sq += nrm_p[t][k];
    rinv[t] = 1.f / fmaxf(sqrtf(sq), 1e-12f);
  }
  __syncthreads();
  #pragma unroll
  for (int k = 0; k < 16; ++k) {
    int idx = t + k*512;
    int node = idx >> 7, c = idx & 127;
    hs[node][c] = fmaxf(hs[node][c]*rinv[node], 0.f);
  }
  __syncthreads();

  for (int l = 0; l < 2; ++l) {
    float4 bv = *(const float4*)(blin + l*128 + c0);
    float a2[4][4];
    #pragma unroll
    for (int nd = 0; nd < 4; ++nd) {
      a2[nd][0]=bv.x; a2[nd][1]=bv.y; a2[nd][2]=bv.z; a2[nd][3]=bv.w;
    }
    for (int i = 0; i < 128; i += 4) {
      float av[4][4];
      #pragma unroll
      for (int nd = 0; nd < 4; ++nd)
        *(float4*)av[nd] = *(const float4*)&hs[nb+nd][i];
      #pragma unroll
      for (int ii = 0; ii < 4; ++ii) {
        float4 wv = *(const float4*)(Wlin + l*16384 + (i+ii)*128 + c0);
        #pragma unroll
        for (int nd = 0; nd < 4; ++nd) {
          a2[nd][0] += av[nd][ii]*wv.x;
          a2[nd][1] += av[nd][ii]*wv.y;
          a2[nd][2] += av[nd][ii]*wv.z;
          a2[nd][3] += av[nd][ii]*wv.w;
        }
      }
    }
    __syncthreads();
    #pragma unroll
    for (int nd = 0; nd < 4; ++nd)
      *(float4*)&hs[nb+nd][c0] = make_float4(
          fmaxf(a2[nd][0],0.f), fmaxf(a2[nd][1],0.f),
          fmaxf(a2[nd][2],0.f), fmaxf(a2[nd][3],0.f));
    __syncthreads();
  }

  if (t < 128) {
    int c = t;
    float accm = 0.f; int gprev = -1;
    for (int nn = 0; nn < HD_NODES; ++nn) {
      int n = n0 + nn;
      if (n >= N) break;
      int g = bseg[n];
      if (g != gprev) {
        if (gprev >= 0) atomicAdd(&m[gprev*128 + c], accm);
        accm = 0.f; gprev = g;
      }
      accm += (float)outdeg[n]*hs[nn][c];
    }
    if (gprev >= 0) atomicAdd(&m[gprev*128 + c], accm);
  } else if (t == 128) {
    float a = 0.f; int gp = -1;
    for (int nn = 0; nn < HD_NODES; ++nn) {
      int n = n0 + nn;
      if (n >= N) break;
      int g = bseg[n];
      if (g != gp) {
        if (gp >= 0) atomicAdd(&cg[gp], a);
        a = 0.f; gp = g;
      }
      a += (float)outdeg[n];
    }
    if (gp >= 0) atomicAdd(&cg[gp], a);
  }
}

// ---- final: softmax((m/cg) @ Wout + bout) ----
__global__ void k_out(const float* __restrict__ m, const float* __restrict__ cg,
                      const float* __restrict__ Wout, const float* __restrict__ bout,
                      float* __restrict__ out)
{
  int g = threadIdx.x;
  if (g >= NG) return;
  float inv = 1.f / fmaxf(cg[g], 1.f);
  float v[9];
  #pragma unroll
  for (int j = 0; j < 9; ++j) {
    float a = 0.f;
    for (int i = 0; i < 128; ++i) a += m[g*128 + i]*Wout[i*9 + j];
    v[j] = a*inv + bout[j];
  }
  float mxv = v[0];
  #pragma unroll
  for (int j = 1; j < 9; ++j) mxv = fmaxf(mxv, v[j]);
  float sum = 0.f;
  #pragma unroll
  for (int j = 0; j < 9; ++j) { v[j] = expf(v[j] - mxv); sum += v[j]; }
  #pragma unroll
  for (int j = 0; j < 9; ++j) out[g*9 + j] = v[j]/sum;
}

extern "C" void kernel_launch(void* const* d_in, const int* in_sizes, int n_in,
                              void* d_out, int out_size, void* d_ws, size_t ws_size,
                              hipStream_t stream) {
  (void)in_sizes; (void)n_in; (void)out_size; (void)ws_size;
  const float* x_scalars = (const float*)d_in[0];
  const float* edge_vec  = (const float*)d_in[1];
  const float* et0_W0    = (const float*)d_in[2];
  const float* et0_W1    = (const float*)d_in[3];
  const float* et0_W2    = (const float*)d_in[4];
  const float* et0_Wd    = (const float*)d_in[5];
  const float* h_W0      = (const float*)d_in[6];
  const float* h_W1      = (const float*)d_in[7];
  const float* h_W2      = (const float*)d_in[8];
  const float* h_Wd      = (const float*)d_in[9];
  const float* Wol       = (const float*)d_in[10];
  const float* Wlin      = (const float*)d_in[11];
  const float* blin      = (const float*)d_in[12];
  const float* Wout      = (const float*)d_in[13];
  const float* bout      = (const float*)d_in[14];
  const int*   esrc      = (const int*)d_in[15];
  const int*   edst      = (const int*)d_in[16];
  const int*   bseg      = (const int*)d_in[17];

  const int N = NN, E = NE;

  char* w = (char*)d_ws;
  auto alloc = [&](size_t nbytes) {
    char* p = w;
    w += (nbytes + 255) & ~(size_t)255;
    return p;
  };
  // deg3: indeg | outdeg | cursor packed -> one memset
  int*   deg3    = (int*)  alloc((size_t)3*N*4);
  int*   indeg   = deg3;
  int*   outdeg  = deg3 + N;
  int*   cursor  = deg3 + 2*N;
  int*   rowptr  = (int*)  alloc((size_t)(N+1)*4);
  int2*  csr     = (int2*) alloc((size_t)E*8);
  float* stA     = (float*)alloc((size_t)N*72*4);
  float* stB     = (float*)alloc((size_t)N*72*4);
  float* qt      = (float*)alloc((size_t)N*QSTRIDE*4);
  float* kv      = (float*)alloc((size_t)N*KVSTRIDE*4);
  float* pool    = (float*)alloc((size_t)(NG*128 + NG)*4);
  float* mpool   = pool;
  float* cgp     = pool + NG*128;

  hipMemsetAsync(deg3, 0, (size_t)3*N*4, stream);
  hipMemsetAsync(pool, 0, (size_t)(NG*128 + NG)*4, stream);

  const int TB = 256;
  const int gE  = (E + TB - 1) / TB;
  const int gN  = (N + TB - 1) / TB;
  const int gA2 = (N + AT2_NPB - 1) / AT2_NPB;
  const int gHD = (N + HD_NODES - 1) / HD_NODES;

  // CSR build
  k_count<<<gE, TB, 0, stream>>>(esrc, edst, indeg, outdeg, E);
  k_prefix<<<1, 1024, 0, stream>>>(indeg, rowptr, N);
  k_fill<<<gE, TB, 0, stream>>>(esrc, edst, rowptr, cursor, csr, E);

  // ---- et0 layer (sh-init fused; no residual) ----
  k_node_feats<10,1,true><<<gN, TB, 0, stream>>>(
      x_scalars, edge_vec, csr, rowptr,
      et0_W0, et0_W1, et0_W2, et0_Wd, qt, kv, N);
  k_attn2<<<gA2, 256, 0, stream>>>(qt, kv, csr, rowptr, nullptr, stA, N);

  // ---- 2 hidden layers with residual ----
  float* cur = stA; float* oth = stB;
  for (int l = 0; l < 2; ++l) {
    k_node_feats<8,8,false><<<gN, TB, 0, stream>>>(
        cur, nullptr, nullptr, nullptr,
        h_W0 + l*192, h_W1 + l*192, h_W2 + l*192, h_Wd + l*192, qt, kv, N);
    k_attn2<<<gA2, 256, 0, stream>>>(qt, kv, csr, rowptr, cur, oth, N);
    float* t = cur; cur = oth; oth = t;
  }

  // ---- fused MLP head + group pooling ----
  k_head<<<gHD, 512, 0, stream>>>(cur, Wol, Wlin, blin, outdeg, bseg, mpool, cgp, N);
  k_out<<<1, 64, 0, stream>>>(mpool, cgp, Wout, bout, (float*)d_out);
}